// Round 8
// baseline (4474.645 us; speedup 1.0000x reference)
//
#include <hip/hip_runtime.h>
#include <hip/hip_bf16.h>

#define DD 128            // codebook dim

__global__ void plant_diag(float val, float* out) {
    if (threadIdx.x == 0 && blockIdx.x == 0) out[0] = val;
}

__global__ void zero_acc(double* acc) {
    if (threadIdx.x == 0 && blockIdx.x == 0) { acc[0] = 0.0; acc[1] = 0.0; }
}

// ---------------- silu mimicking np: x * (1/(1+exp(-x))), each op f32-rounded;
// exp = f64 exp rounded to f32 (correctly-rounded f32 exp) ----------------
__device__ __forceinline__ float silu_np(float x) {
    float e = (float)exp(-(double)x);   // correctly-rounded f32 exp
    float u = 1.0f + e;                 // f32 add
    float v = 1.0f / u;                 // f32 div (IEEE)
    return x * v;                       // f32 mul
}

// ---------------- sequential-FMA GEMM: C = act(A@W + b), np/BLAS-faithful ----------------
// Each C[m,n] = fmaf chain over k ASCENDING (matches OpenBLAS/Eigen sgemm accumulation),
// then one f32 bias add, then silu (f32 ops). 8 rows/block, 256 n-lanes.
template <bool SILU>
__global__ __launch_bounds__(256) void gemm_seq(const float* __restrict__ A,
                                                const float* __restrict__ W,
                                                const float* __restrict__ bias,
                                                float* __restrict__ C,
                                                int M, int N, int K) {
    extern __shared__ float As[];       // [8][K]
    const int t = threadIdx.x;
    const int n = blockIdx.x * 256 + t;
    const int m0 = blockIdx.y * 8;

    for (int r = 0; r < 8; ++r) {
        int m = m0 + r; if (m >= M) m = M - 1;
        for (int k = t; k < K; k += 256)
            As[r * K + k] = A[(size_t)m * K + k];
    }
    __syncthreads();

    if (n >= N) return;

    float a0 = 0.f, a1 = 0.f, a2 = 0.f, a3 = 0.f, a4 = 0.f, a5 = 0.f, a6 = 0.f, a7 = 0.f;
    for (int k = 0; k < K; ++k) {
        float w = W[(size_t)k * N + n];
        a0 = fmaf(As[0 * K + k], w, a0);
        a1 = fmaf(As[1 * K + k], w, a1);
        a2 = fmaf(As[2 * K + k], w, a2);
        a3 = fmaf(As[3 * K + k], w, a3);
        a4 = fmaf(As[4 * K + k], w, a4);
        a5 = fmaf(As[5 * K + k], w, a5);
        a6 = fmaf(As[6 * K + k], w, a6);
        a7 = fmaf(As[7 * K + k], w, a7);
    }
    float accs[8] = {a0, a1, a2, a3, a4, a5, a6, a7};
    const float b = bias[n];
    const int rows = (M - m0 < 8) ? (M - m0) : 8;
    for (int r = 0; r < rows; ++r) {
        float x = accs[r] + b;          // f32 add (np: matmul then +bias)
        if (SILU) x = silu_np(x);
        C[(size_t)(m0 + r) * N + n] = x;
    }
}

// ---------------- t2[k] = np-pairwise-sum over 128 of cb[k,:]^2 (f32) ----------------
// numpy pairwise for n=128: 8 accumulators r[j] over p[8i+j], i=0..15, then
// ((r0+r1)+(r2+r3)) + ((r4+r5)+(r6+r7)).
__device__ __forceinline__ float pairwise128_sq(const float* __restrict__ x, int stride) {
    float r0 = x[0*stride]*x[0*stride], r1 = x[1*stride]*x[1*stride],
          r2 = x[2*stride]*x[2*stride], r3 = x[3*stride]*x[3*stride],
          r4 = x[4*stride]*x[4*stride], r5 = x[5*stride]*x[5*stride],
          r6 = x[6*stride]*x[6*stride], r7 = x[7*stride]*x[7*stride];
    for (int i = 8; i < 128; i += 8) {
        r0 += x[(i+0)*stride]*x[(i+0)*stride];
        r1 += x[(i+1)*stride]*x[(i+1)*stride];
        r2 += x[(i+2)*stride]*x[(i+2)*stride];
        r3 += x[(i+3)*stride]*x[(i+3)*stride];
        r4 += x[(i+4)*stride]*x[(i+4)*stride];
        r5 += x[(i+5)*stride]*x[(i+5)*stride];
        r6 += x[(i+6)*stride]*x[(i+6)*stride];
        r7 += x[(i+7)*stride]*x[(i+7)*stride];
    }
    return ((r0 + r1) + (r2 + r3)) + ((r4 + r5) + (r6 + r7));
}

__global__ void code_t2(const float* __restrict__ cb, float* __restrict__ t2, int K) {
    int k = blockIdx.x * 256 + threadIdx.x;
    if (k >= K) return;
    t2[k] = pairwise128_sq(cb + (size_t)k * DD, 1);
}

// ---------------- VQ argmin, np-f32-faithful + fused vq-loss ----------------
// dist[r,k] = f32( f32(t1_r + t2_k) - f32(2 * t3_rk) ),
// t1 = np-pairwise(fl^2), t3 = ascending-d fmaf chain (sgemm order).
// argmin: first-min (ascending k scan, strict <). 16 rows x 16 lanes, 4 codes/lane/chunk.
__global__ __launch_bounds__(256) void vq_np(const float* __restrict__ lat,
                                             const float* __restrict__ cb,
                                             const float* __restrict__ t2,
                                             int* __restrict__ indices,
                                             double* __restrict__ acc, int K) {
    __shared__ float Ls[16][132];
    __shared__ float Cs[128][68];
    __shared__ float T2s[64];
    __shared__ float bv_s[16][17];
    __shared__ int   bk_s[16][17];
    __shared__ double rowval[16];

    const int t = threadIdx.x;
    const int row = t >> 4, cl = t & 15;
    const size_t r0 = (size_t)blockIdx.x * 16;

    for (int e = t; e < 16 * 128; e += 256) {
        int r = e >> 7, d = e & 127;
        Ls[r][d] = lat[(r0 + r) * DD + d];
    }
    __syncthreads();

    // t1 (redundant per lane; identical f32 value)
    const float t1 = pairwise128_sq(&Ls[row][0], 1);

    float bestv = 3.4e38f;
    int bestk = 0;

    for (int k0 = 0; k0 < K; k0 += 64) {
        __syncthreads();
        for (int e = t; e < 64 * 128; e += 256) {
            int c = e >> 7, d = e & 127;
            Cs[d][c] = cb[(size_t)(k0 + c) * DD + d];
        }
        if (t < 64) T2s[t] = t2[k0 + t];
        __syncthreads();

        const int cbase = cl * 4;
        float c0 = 0.f, c1 = 0.f, c2 = 0.f, c3 = 0.f;
        for (int d = 0; d < 128; ++d) {       // ascending d: sgemm chain order
            float a = Ls[row][d];
            c0 = fmaf(a, Cs[d][cbase + 0], c0);
            c1 = fmaf(a, Cs[d][cbase + 1], c1);
            c2 = fmaf(a, Cs[d][cbase + 2], c2);
            c3 = fmaf(a, Cs[d][cbase + 3], c3);
        }
        // dist assembly: each op f32, matching ((t1+t2) - 2*t3)
        float d0 = (t1 + T2s[cbase + 0]) - 2.0f * c0;
        float d1 = (t1 + T2s[cbase + 1]) - 2.0f * c1;
        float d2 = (t1 + T2s[cbase + 2]) - 2.0f * c2;
        float d3 = (t1 + T2s[cbase + 3]) - 2.0f * c3;
        int kb = k0 + cbase;
        if (d0 < bestv) { bestv = d0; bestk = kb + 0; }   // strict <: first-min kept
        if (d1 < bestv) { bestv = d1; bestk = kb + 1; }
        if (d2 < bestv) { bestv = d2; bestk = kb + 2; }
        if (d3 < bestv) { bestv = d3; bestk = kb + 3; }
    }

    bv_s[row][cl] = bestv;
    bk_s[row][cl] = bestk;
    __syncthreads();
    if (cl == 0) {
        float bv = bv_s[row][0];
        int bk = bk_s[row][0];
        for (int j = 1; j < 16; ++j) {
            float v = bv_s[row][j];
            int k = bk_s[row][j];
            if (v < bv || (v == bv && k < bk)) { bv = v; bk = k; }
        }
        indices[r0 + row] = bk;
        rowval[row] = (double)bv;            // dist includes ||l||^2: = min ||l-c||^2
    }
    __syncthreads();
    if (t == 0) {
        double s = 0.0;
        for (int r = 0; r < 16; ++r) s += rowval[r];
        atomicAdd(acc, s);
    }
}

// ---------------- Q gather ----------------
__global__ void q_gather(const int* __restrict__ idx, const float* __restrict__ cb,
                         float* __restrict__ Q, int count, int nlat) {
    int gid = blockIdx.x * 256 + threadIdx.x;
    if (gid >= count) return;
    int m = gid >> 11;            // /2048 (LAT)
    int j = gid & 2047;
    int code = idx[m * nlat + (j >> 7)];
    Q[gid] = cb[((size_t)code << 7) + (j & 127)];
}

// ---------------- recon loss + f32 write ----------------
__global__ __launch_bounds__(256) void recon_out(const float* __restrict__ recon,
                                                 const float* __restrict__ actions,
                                                 float* __restrict__ out,
                                                 double* __restrict__ acc, int count) {
    int gid = blockIdx.x * 256 + threadIdx.x;
    double sq = 0.0;
    if (gid < count) {
        float rv = recon[gid];
        float av = actions[gid];
        double diff = (double)rv - (double)av;
        out[gid] = rv;
        sq = diff * diff;
    }
    __shared__ double red[256];
    red[threadIdx.x] = sq;
    __syncthreads();
    for (int s = 128; s > 0; s >>= 1) {
        if (threadIdx.x < s) red[threadIdx.x] += red[threadIdx.x + s];
        __syncthreads();
    }
    if (threadIdx.x == 0) atomicAdd(acc + 1, red[0]);
}

__global__ void idx_out(const int* __restrict__ idx, float* __restrict__ out, int count) {
    int gid = blockIdx.x * 256 + threadIdx.x;
    if (gid < count) out[gid] = (float)idx[gid];
}

__global__ void finalize(const double* __restrict__ acc, float* __restrict__ out,
                         double vq_den, double rec_den) {
    double vq = 1.25 * acc[0] / vq_den;
    double rl = acc[1] / rec_den;
    out[0] = (float)vq;
    out[1] = (float)rl;
    out[2] = (float)(rl + vq);
}

static inline int ceildiv(int a, int b) { return (a + b - 1) / b; }

// ---------------- launch ----------------
extern "C" void kernel_launch(void* const* d_in, const int* in_sizes, int n_in,
                              void* d_out, int out_size, void* d_ws, size_t ws_size,
                              hipStream_t stream) {
    const float* actions = (const float*)d_in[0];
    const float* e_w1 = (const float*)d_in[1];
    const float* e_b1 = (const float*)d_in[2];
    const float* e_w2 = (const float*)d_in[3];
    const float* e_b2 = (const float*)d_in[4];
    const float* e_w3 = (const float*)d_in[5];
    const float* e_b3 = (const float*)d_in[6];
    const float* cb   = (const float*)d_in[7];
    const float* d_w1 = (const float*)d_in[8];
    const float* d_b1 = (const float*)d_in[9];
    const float* d_w2 = (const float*)d_in[10];
    const float* d_b2 = (const float*)d_in[11];
    const float* d_w3 = (const float*)d_in[12];
    const float* d_b3 = (const float*)d_in[13];
    float* out = (float*)d_out;                 // f32 output (confirmed round 7)

    const int FLAT = in_sizes[13];
    const int B    = in_sizes[0] / FLAT;
    const int HID  = in_sizes[2];
    const int LAT  = in_sizes[6];
    const int K    = in_sizes[7] / DD;
    const int NL   = LAT / DD;

    // chunked pipeline (all f32 buffers now)
    int CHUNK = B < 1024 ? B : 1024;
    auto need = [&](int ch) -> size_t {
        return (size_t)ch * HID * 4 * 2      // h1c,h2c
             + (size_t)ch * LAT * 4 * 2      // latc, Qc
             + (size_t)ch * HID * 4 * 2      // g1c,g2c
             + (size_t)ch * FLAT * 4         // recc
             + (size_t)K * 4 + 64            // t2 + acc
             + (size_t)B * NL * 4;           // idx
    };
    while (CHUNK > 16 && need(CHUNK) > ws_size) CHUNK >>= 1;
    if (need(CHUNK) > ws_size) {
        plant_diag<<<1, 64, 0, stream>>>(2222.0f, out);
        return;
    }
    const int NCHUNK = ceildiv(B, CHUNK);

    char* ws = (char*)d_ws;
    size_t off = 0;
    float* h1c  = (float*)(ws + off); off += (size_t)CHUNK * HID * 4;
    float* h2c  = (float*)(ws + off); off += (size_t)CHUNK * HID * 4;
    float* latc = (float*)(ws + off); off += (size_t)CHUNK * LAT * 4;
    float* Qc   = (float*)(ws + off); off += (size_t)CHUNK * LAT * 4;
    float* g1c  = (float*)(ws + off); off += (size_t)CHUNK * HID * 4;
    float* g2c  = (float*)(ws + off); off += (size_t)CHUNK * HID * 4;
    float* recc = (float*)(ws + off); off += (size_t)CHUNK * FLAT * 4;
    float* t2   = (float*)(ws + off); off += (size_t)K * 4;
    double* acc = (double*)(ws + off); off += 64;
    int*   idx  = (int*)(ws + off);

    zero_acc<<<1, 64, 0, stream>>>(acc);
    code_t2<<<ceildiv(K, 256), 256, 0, stream>>>(cb, t2, K);

    for (int c = 0; c < NCHUNK; ++c) {
        const int r0 = c * CHUNK;
        const int cbR = (B - r0 < CHUNK) ? (B - r0) : CHUNK;
        const float* act_c = actions + (size_t)r0 * FLAT;
        int* idx_c = idx + (size_t)r0 * NL;

        // encoder: np-f32-faithful sequential-FMA chains
        gemm_seq<true><<<dim3(ceildiv(HID, 256), ceildiv(cbR, 8)), 256, 8 * FLAT * 4, stream>>>(
            act_c, e_w1, e_b1, h1c, cbR, HID, FLAT);
        gemm_seq<true><<<dim3(ceildiv(HID, 256), ceildiv(cbR, 8)), 256, 8 * HID * 4, stream>>>(
            h1c, e_w2, e_b2, h2c, cbR, HID, HID);
        gemm_seq<false><<<dim3(ceildiv(LAT, 256), ceildiv(cbR, 8)), 256, 8 * HID * 4, stream>>>(
            h2c, e_w3, e_b3, latc, cbR, LAT, HID);

        // VQ: np-f32 dist quantization + first-min argmin (rows = cbR*NL, multiple of 16)
        vq_np<<<(cbR * NL) / 16, 256, 0, stream>>>(latc, cb, t2, idx_c, acc, K);

        // decoder (loose tolerance)
        q_gather<<<ceildiv(cbR * LAT, 256), 256, 0, stream>>>(idx_c, cb, Qc, cbR * LAT, NL);
        gemm_seq<true><<<dim3(ceildiv(HID, 256), ceildiv(cbR, 8)), 256, 8 * LAT * 4, stream>>>(
            Qc, d_w1, d_b1, g1c, cbR, HID, LAT);
        gemm_seq<true><<<dim3(ceildiv(HID, 256), ceildiv(cbR, 8)), 256, 8 * HID * 4, stream>>>(
            g1c, d_w2, d_b2, g2c, cbR, HID, HID);
        gemm_seq<false><<<dim3(ceildiv(FLAT, 256), ceildiv(cbR, 8)), 256, 8 * HID * 4, stream>>>(
            g2c, d_w3, d_b3, recc, cbR, FLAT, HID);

        recon_out<<<ceildiv(cbR * FLAT, 256), 256, 0, stream>>>(
            recc, act_c, out + (size_t)r0 * FLAT, acc, cbR * FLAT);
    }

    // f32 packing: [ recon B*FLAT | indices B*NL | vq, recon_loss, loss ]
    idx_out<<<ceildiv(B * NL, 256), 256, 0, stream>>>(idx, out + (size_t)B * FLAT, B * NL);
    finalize<<<1, 1, 0, stream>>>(acc, out + (size_t)B * FLAT + (size_t)B * NL,
                                  (double)B * NL * DD, (double)B * FLAT);
}